// Round 11
// baseline (57.757 us; speedup 1.0000x reference)
//
#include <hip/hip_runtime.h>
#include <math.h>

typedef __attribute__((ext_vector_type(8))) short short8;
typedef __attribute__((ext_vector_type(4))) float f32x4;
typedef unsigned short ushort_t;
typedef unsigned int uint_t;

#define HH 128
#define WW 128
#define CC 64
#define HWp 16384

__device__ inline ushort_t f2bf(float f) {
    uint_t u = __float_as_uint(f);
    uint_t r = (u + 0x7FFFu + ((u >> 16) & 1u)) >> 16;
    return (ushort_t)r;
}
__device__ inline float blo(uint_t u) { return __uint_as_float(u << 16); }
__device__ inline float bhi(uint_t u) { return __uint_as_float(u & 0xFFFF0000u); }
__device__ inline short8 bc8(uint4 v) { return __builtin_bit_cast(short8, v); }

__device__ inline uint_t pk2(f32x4 wv, uint_t a, uint_t b, uint_t c, uint_t d) {
    float lo = wv.x * blo(a) + wv.y * blo(b) + wv.z * blo(c) + wv.w * blo(d);
    float hi = wv.x * bhi(a) + wv.y * bhi(b) + wv.z * bhi(c) + wv.w * bhi(d);
    uint_t r;
    asm("v_cvt_pk_bf16_f32 %0, %1, %2" : "=v"(r) : "v"(lo), "v"(hi));
    return r;
}
__device__ inline short8 bilerp8(f32x4 wv, uint4 A, uint4 B, uint4 C, uint4 D) {
    uint4 r;
    r.x = pk2(wv, A.x, B.x, C.x, D.x);
    r.y = pk2(wv, A.y, B.y, C.y, D.y);
    r.z = pk2(wv, A.z, B.z, C.z, D.z);
    r.w = pk2(wv, A.w, B.w, C.w, D.w);
    return __builtin_bit_cast(short8, r);
}

// ---------------- weight packing into MFMA A-fragment order -----------------
__global__ __launch_bounds__(256) void k_pack(const float* __restrict__ w_off,
        const float* __restrict__ w_mask, const float* __restrict__ w,
        ushort_t* __restrict__ wpom, ushort_t* __restrict__ wpm) {
    int idx = blockIdx.x * 256 + threadIdx.x;
    if (idx < 18432) {
        int e = idx;
        int j = e & 7, l = (e >> 3) & 63, mf = (e >> 9) & 1, ks = e >> 10;
        int ch = mf * 16 + (l & 15);
        int k = ks * 32 + ((l >> 4) << 3) + j;
        int c = k & 63, kk = k >> 6;
        float v = 0.f;
        if (ch < 18) v = w_off[(ch * CC + c) * 9 + kk];
        else if (ch < 27) v = w_mask[((ch - 18) * CC + c) * 9 + kk];
        wpom[idx] = f2bf(v);
    } else if (idx < 18432 + 36864) {
        int e = idx - 18432;
        int j = e & 7, l = (e >> 3) & 63, mf = (e >> 9) & 3, ks = e >> 11;
        int o = mf * 16 + (l & 15);
        int k = ks * 32 + ((l >> 4) << 3) + j;
        int c = k & 63, kk = k >> 6;
        wpm[e] = f2bf(w[(o * CC + c) * 9 + kk]);
    }
}

// ---------------- merged: x transpose (bid<1024)  ||  om conv (bid>=1024) ---
// The conv branch reads x (NCHW f32) DIRECTLY — no xtb dependency — so both
// phases overlap in one dispatch. Same RNE bf16 rounding -> identical results.
__global__ __launch_bounds__(256, 6) void k_stage(const float* __restrict__ x,
        ushort_t* __restrict__ xtb, const uint4* __restrict__ wpom,
        const float* __restrict__ b_off, const float* __restrict__ b_mask,
        float* __restrict__ om) {
    __shared__ __align__(16) char ldsbuf[3 * 68 * 64 * 2];   // 26112 B union
    int bid = blockIdx.x;
    int t = threadIdx.x;

    if (bid < 1024) {
        // ---- transpose branch: NCHW f32 -> NHWC bf16 ----
        float (*tile)[68] = (float (*)[68])ldsbuf;           // 64 x 68 f32
        int xs = (bid & 1) * 64;
        int y  = (bid >> 1) & 127;
        int b  = bid >> 8;
#pragma unroll
        for (int i = 0; i < 4; ++i) {
            int c  = i * 16 + (t >> 4);
            int xl = (t & 15) << 2;
            float4 v = *(const float4*)&x[(((size_t)b * CC + c) * HH + y) * WW + xs + xl];
            *(float4*)&tile[c][xl] = v;
        }
        __syncthreads();
#pragma unroll
        for (int i = 0; i < 8; ++i) {
            int pxl = i * 8 + (t >> 5);
            int cp  = t & 31;
            float v0 = tile[cp * 2][pxl], v1 = tile[cp * 2 + 1][pxl];
            uint_t pk;
            asm("v_cvt_pk_bf16_f32 %0, %1, %2" : "=v"(pk) : "v"(v0), "v"(v1));
            *(uint_t*)&xtb[(((size_t)b * HH + y) * WW + xs + pxl) * CC + cp * 2] = pk;
        }
        return;
    }

    // ---- conv branch: offset/mask conv as MFMA GEMM, reads x f32 direct ----
    ushort_t* xrow = (ushort_t*)ldsbuf;        // [3][68][64], idx ^= (cl&7)<<3
    int rem = bid - 1024;
    int b = rem >> 8;
    int y = (rem >> 1) & 127;
    int xh = (rem & 1) * 64;
    int lane = t & 63, w = t >> 6;

    // interior columns cl = 1..64  (x-coord = xh + lane, always in-bounds)
#pragma unroll
    for (int r = 0; r < 24; ++r) {
        int ky = r >> 3;                        // 0..2
        int cp = (w << 3) + (r & 7);            // 0..31, wave-partitioned
        int yy = y + ky - 1;
        bool rok = (yy >= 0) && (yy < HH);
        float v0 = 0.f, v1 = 0.f;
        if (rok) {
            size_t base = ((size_t)(b * CC + cp * 2) * HH + yy) * WW + xh + lane;
            v0 = x[base];
            v1 = x[base + (size_t)HWp];
        }
        uint_t pk;
        asm("v_cvt_pk_bf16_f32 %0, %1, %2" : "=v"(pk) : "v"(v0), "v"(v1));
        int cl = lane + 1;
        int idx = ((ky * 68 + cl) * 64 + cp * 2) ^ ((cl & 7) << 3);
        *(uint_t*)&xrow[idx] = pk;
    }
    // edge columns cl = 0 (x = xh-1) and cl = 65 (x = xh+64)
    if (t < 192) {
        int ky = t >> 6, rr = t & 63, cp = rr >> 1, side = rr & 1;
        int yy = y + ky - 1;
        int xcoord = side ? xh + 64 : xh - 1;
        bool ok = (yy >= 0) && (yy < HH) && (xcoord >= 0) && (xcoord < WW);
        float v0 = 0.f, v1 = 0.f;
        if (ok) {
            size_t base = ((size_t)(b * CC + cp * 2) * HH + yy) * WW + xcoord;
            v0 = x[base];
            v1 = x[base + (size_t)HWp];
        }
        uint_t pk;
        asm("v_cvt_pk_bf16_f32 %0, %1, %2" : "=v"(pk) : "v"(v0), "v"(v1));
        int cl = side ? 65 : 0;
        int idx = ((ky * 68 + cl) * 64 + cp * 2) ^ ((cl & 7) << 3);
        *(uint_t*)&xrow[idx] = pk;
    }
    __syncthreads();

    int lm = lane & 15, lg = lane >> 4;
    int pxl = w * 16 + lm;                     // 0..63 local
    f32x4 acc[2] = {};
#pragma unroll
    for (int ks = 0; ks < 18; ++ks) {
        int kk = ks >> 1;
        int kyy = kk / 3, kxx = kk % 3;
        int c0 = (ks & 1) * 32 + lg * 8;
        short8 a0 = bc8(wpom[(ks * 2 + 0) * 64 + lane]);
        short8 a1 = bc8(wpom[(ks * 2 + 1) * 64 + lane]);
        int cl = pxl + kxx;
        int idx = ((kyy * 68 + cl) * 64 + c0) ^ ((cl & 7) << 3);
        short8 bf = *(const short8*)&xrow[idx];
        acc[0] = __builtin_amdgcn_mfma_f32_16x16x32_bf16(a0, bf, acc[0], 0, 0, 0);
        acc[1] = __builtin_amdgcn_mfma_f32_16x16x32_bf16(a1, bf, acc[1], 0, 0, 0);
    }
    int xg = (xh >> 4) + w;                    // tile index 0..7
    size_t tb = ((size_t)((b * 128 + y) * 8 + xg)) * 432;
#pragma unroll
    for (int mf = 0; mf < 2; ++mf)
#pragma unroll
        for (int r = 0; r < 4; ++r) {
            int ch = mf * 16 + lg * 4 + r;
            if (ch < 27) {
                float v = acc[mf][r] + (ch < 18 ? b_off[ch] : b_mask[ch - 18]);
                if (ch >= 18) v = 1.f / (1.f + __expf(-v));
                om[tb + ch * 16 + lm] = v;
            }
        }
}

// ---------------- fused deform-gather + main GEMM (16 px, 256 thr) ----------
__global__ __launch_bounds__(256, 8) void k_fused(const ushort_t* __restrict__ xtb,
        const float* __restrict__ omt, const uint4* __restrict__ wpm,
        const float* __restrict__ bias, float* __restrict__ out) {
    __shared__ __align__(16) ushort_t sm[16 * 576];    // idx ^= ((px^k)&7)<<3
    int blk = blockIdx.x;                              // 4096
    int b = blk >> 10, rem = blk & 1023;
    int y = rem >> 3, xg = rem & 7, xs = xg << 4;
    int t = threadIdx.x, lane = t & 63, w = t >> 6;    // 4 waves
    const char* xbB = (const char*)xtb + ((size_t)b << 21);
    const float* omb = omt + ((size_t)((b * 128 + y) * 8 + xg)) * 432;

    // ---- phase 0: wave-local params in REGISTERS (lanes 0..35) ----
    float pw0 = 0.f, pw1 = 0.f, pw2 = 0.f, pw3 = 0.f;
    int paT = 0, paB = 0, ppk = 0;
    if (lane < 36) {
        int pxl = lane / 9, k = lane - pxl * 9;
        int px_t = (w << 2) + pxl;             // 0..15 in tile
        int ki = k / 3, kj = k - ki * 3;
        int x = xs + px_t;
        float dy = omb[32 * k + px_t];
        float dx = omb[32 * k + 16 + px_t];
        float m  = omb[288 + 16 * k + px_t];
        float sy = (float)(y - 1 + ki) + dy;
        float sx = (float)(x - 1 + kj) + dx;
        float fy = floorf(sy), fx = floorf(sx);
        float wy1 = sy - fy, wx1 = sx - fx;
        float wy0 = 1.f - wy1, wx0 = 1.f - wx1;
        int iy0 = (int)fy, ix0 = (int)fx;
        int iy1 = iy0 + 1, ix1 = ix0 + 1;
        bool vy0 = (iy0 >= 0) & (iy0 < HH);
        bool vy1 = (iy1 >= 0) & (iy1 < HH);
        float wyr0 = vy0 ? wy0 : (vy1 ? wy1 : 0.f);
        int   ry0  = vy0 ? iy0 : (vy1 ? iy1 : 0);
        float wyr1 = (vy0 & vy1) ? wy1 : 0.f;
        int   ry1  = min(max(iy1, 0), HH - 1);
        int bx = min(max(ix0, 0), WW - 2);
        float wxh0 = (bx == ix0) ? wx0 : ((bx == ix1) ? wx1 : 0.f);
        float wxh1 = (bx + 1 == ix1) ? wx1 : ((bx + 1 == ix0) ? wx0 : 0.f);
        pw0 = m * wyr0 * wxh0;
        pw1 = m * wyr0 * wxh1;
        pw2 = m * wyr1 * wxh0;
        pw3 = m * wyr1 * wxh1;
        paT = (int)((uint_t)(((ry0 << 7) + bx) << 7));
        paB = (int)((uint_t)(((ry1 << 7) + bx) << 7));
        ppk = (int)((uint_t)(px_t * 576 + k * 64) |
                    ((uint_t)(((px_t ^ k) & 7) << 3) << 16));
    }

    // ---- phase 1: 8-lane group = 1 sample, params via __shfl, pipelined ----
    {
        int g = lane >> 3, j = lane & 7;
        uint_t j16 = (uint_t)(j << 4);
        uint_t jw  = (uint_t)(j << 3);
        int slA = g;                            // round 0 sample
        float wA0 = __shfl(pw0, slA), wA1 = __shfl(pw1, slA);
        float wA2 = __shfl(pw2, slA), wA3 = __shfl(pw3, slA);
        uint_t aTA = (uint_t)__shfl(paT, slA) + j16;
        uint_t aBA = (uint_t)__shfl(paB, slA) + j16;
        uint_t pkA = (uint_t)__shfl(ppk, slA);
        uint4 tlA = *(const uint4*)(xbB + aTA);
        uint4 trA = *(const uint4*)(xbB + aTA + 128);
        uint4 blA = *(const uint4*)(xbB + aBA);
        uint4 brA = *(const uint4*)(xbB + aBA + 128);
#pragma unroll
        for (int r = 0; r < 5; ++r) {
            float wB0, wB1, wB2, wB3;
            uint_t pkB = 0;
            uint4 tlB, trB, blB, brB;
            if (r < 4) {
                int slB = g + (r + 1) * 8; slB = slB > 35 ? 35 : slB;
                wB0 = __shfl(pw0, slB); wB1 = __shfl(pw1, slB);
                wB2 = __shfl(pw2, slB); wB3 = __shfl(pw3, slB);
                uint_t aTB = (uint_t)__shfl(paT, slB) + j16;
                uint_t aBB = (uint_t)__shfl(paB, slB) + j16;
                pkB = (uint_t)__shfl(ppk, slB);
                tlB = *(const uint4*)(xbB + aTB);
                trB = *(const uint4*)(xbB + aTB + 128);
                blB = *(const uint4*)(xbB + aBB);
                brB = *(const uint4*)(xbB + aBB + 128);
            }
            f32x4 wv = { wA0, wA1, wA2, wA3 };
            short8 bf = bilerp8(wv, tlA, trA, blA, brA);
            if (r < 4 || g < 4) {
                uint_t widx = ((pkA & 0xFFFFu) + jw) ^ (pkA >> 16);
                *(short8*)&sm[widx] = bf;
            }
            wA0 = wB0; wA1 = wB1; wA2 = wB2; wA3 = wB3;
            pkA = pkB;
            tlA = tlB; trA = trB; blA = blB; brA = brB;
        }
    }
    __syncthreads();

    // ---- phase 2: out[64 x 16] = W(64x576) . sm(576x16); wave = mfrag ----
    int lm = lane & 15, lg = lane >> 4;
    f32x4 acc = {};
#pragma unroll
    for (int ks = 0; ks < 18; ++ks) {
        short8 af = bc8(wpm[((ks << 2) + w) * 64 + lane]);
        int bidx = (lm * 576 + (ks << 5) + (lg << 3)) ^ (((lm ^ (ks >> 1)) & 7) << 3);
        short8 bf = *(const short8*)&sm[bidx];
        acc = __builtin_amdgcn_mfma_f32_16x16x32_bf16(af, bf, acc, 0, 0, 0);
    }
#pragma unroll
    for (int r = 0; r < 4; ++r) {
        int o = (w << 4) + (lg << 2) + r;
        out[(((size_t)b * 64 + o) << 14) + (y << 7) + xs + lm] = acc[r] + bias[o];
    }
}

extern "C" void kernel_launch(void* const* d_in, const int* in_sizes, int n_in,
                              void* d_out, int out_size, void* d_ws, size_t ws_size,
                              hipStream_t stream) {
    const float* x      = (const float*)d_in[0];
    const float* w_off  = (const float*)d_in[1];
    const float* b_off  = (const float*)d_in[2];
    const float* w_mask = (const float*)d_in[3];
    const float* b_mask = (const float*)d_in[4];
    const float* w      = (const float*)d_in[5];
    const float* bias   = (const float*)d_in[6];
    float* out = (float*)d_out;

    char* ws = (char*)d_ws;
    ushort_t* xtb  = (ushort_t*)(ws);                    //  8,388,608 B
    float*    om   = (float*)(ws + 8388608);             //  7,077,888 B (tiled)
    ushort_t* wpom = (ushort_t*)(ws + 15466496);         //     36,864 B
    ushort_t* wpm  = (ushort_t*)(ws + 15503360);         //     73,728 B

    hipLaunchKernelGGL(k_pack, dim3(216), dim3(256), 0, stream,
                       w_off, w_mask, w, wpom, wpm);
    hipLaunchKernelGGL(k_stage, dim3(2048), dim3(256), 0, stream,
                       x, xtb, (const uint4*)wpom, b_off, b_mask, om);
    hipLaunchKernelGGL(k_fused, dim3(4096), dim3(256), 0, stream,
                       xtb, om, (const uint4*)wpm, bias, out);
}

// Round 12
// 48.561 us; speedup vs baseline: 1.1894x; 1.1894x over previous
//
#include <hip/hip_runtime.h>
#include <math.h>

typedef __attribute__((ext_vector_type(8))) short short8;
typedef __attribute__((ext_vector_type(4))) float f32x4;
typedef unsigned short ushort_t;
typedef unsigned int uint_t;

#define HH 128
#define WW 128
#define CC 64
#define HWp 16384

__device__ inline ushort_t f2bf(float f) {
    uint_t u = __float_as_uint(f);
    uint_t r = (u + 0x7FFFu + ((u >> 16) & 1u)) >> 16;
    return (ushort_t)r;
}
__device__ inline float blo(uint_t u) { return __uint_as_float(u << 16); }
__device__ inline float bhi(uint_t u) { return __uint_as_float(u & 0xFFFF0000u); }
__device__ inline short8 bc8(uint4 v) { return __builtin_bit_cast(short8, v); }

__device__ inline uint_t pk2(f32x4 wv, uint_t a, uint_t b, uint_t c, uint_t d) {
    float lo = wv.x * blo(a) + wv.y * blo(b) + wv.z * blo(c) + wv.w * blo(d);
    float hi = wv.x * bhi(a) + wv.y * bhi(b) + wv.z * bhi(c) + wv.w * bhi(d);
    uint_t r;
    asm("v_cvt_pk_bf16_f32 %0, %1, %2" : "=v"(r) : "v"(lo), "v"(hi));
    return r;
}
__device__ inline short8 bilerp8(f32x4 wv, uint4 A, uint4 B, uint4 C, uint4 D) {
    uint4 r;
    r.x = pk2(wv, A.x, B.x, C.x, D.x);
    r.y = pk2(wv, A.y, B.y, C.y, D.y);
    r.z = pk2(wv, A.z, B.z, C.z, D.z);
    r.w = pk2(wv, A.w, B.w, C.w, D.w);
    return __builtin_bit_cast(short8, r);
}

// ---------------- prep: x transpose (blocks 0..1023) + weight pack ----------
__global__ __launch_bounds__(256) void k_prep(const float* __restrict__ x,
        ushort_t* __restrict__ xtb,
        const float* __restrict__ w_off, const float* __restrict__ w_mask,
        const float* __restrict__ w,
        ushort_t* __restrict__ wpom, ushort_t* __restrict__ wpm) {
    __shared__ __align__(16) float tile[64][68];
    int bid = blockIdx.x;
    int t = threadIdx.x;
    if (bid < 1024) {
        int xs = (bid & 1) * 64;
        int y  = (bid >> 1) & 127;
        int b  = bid >> 8;
#pragma unroll
        for (int i = 0; i < 4; ++i) {
            int c  = i * 16 + (t >> 4);
            int xl = (t & 15) << 2;
            float4 v = *(const float4*)&x[(((size_t)b * CC + c) * HH + y) * WW + xs + xl];
            *(float4*)&tile[c][xl] = v;
        }
        __syncthreads();
#pragma unroll
        for (int i = 0; i < 8; ++i) {
            int pxl = i * 8 + (t >> 5);
            int cp  = t & 31;
            float v0 = tile[cp * 2][pxl], v1 = tile[cp * 2 + 1][pxl];
            uint_t pk;
            asm("v_cvt_pk_bf16_f32 %0, %1, %2" : "=v"(pk) : "v"(v0), "v"(v1));
            *(uint_t*)&xtb[(((size_t)b * HH + y) * WW + xs + pxl) * CC + cp * 2] = pk;
        }
    } else {
        int idx = (bid - 1024) * 256 + t;
        if (idx < 18432) {
            int e = idx;
            int j = e & 7, l = (e >> 3) & 63, mf = (e >> 9) & 1, ks = e >> 10;
            int ch = mf * 16 + (l & 15);
            int k = ks * 32 + ((l >> 4) << 3) + j;
            int c = k & 63, kk = k >> 6;
            float v = 0.f;
            if (ch < 18) v = w_off[(ch * CC + c) * 9 + kk];
            else if (ch < 27) v = w_mask[((ch - 18) * CC + c) * 9 + kk];
            wpom[idx] = f2bf(v);
        } else if (idx < 18432 + 36864) {
            int e = idx - 18432;
            int j = e & 7, l = (e >> 3) & 63, mf = (e >> 9) & 3, ks = e >> 11;
            int o = mf * 16 + (l & 15);
            int k = ks * 32 + ((l >> 4) << 3) + j;
            int c = k & 63, kk = k >> 6;
            wpm[e] = f2bf(w[(o * CC + c) * 9 + kk]);
        }
    }
}

// ---------------- offset/mask conv as MFMA GEMM (32 px, 256 thr) ------------
// 2048 blocks -> 8 blocks/CU (32 waves, full). LDS 13 KB, 3 x 34-col halo.
// om output TILED: om[((b*128+y)*8 + xg)*432 + ch*16 + px'].
__global__ __launch_bounds__(256, 8) void k_conv_om(const ushort_t* __restrict__ xtb,
        const uint4* __restrict__ wpom, const float* __restrict__ b_off,
        const float* __restrict__ b_mask, float* __restrict__ om) {
    __shared__ ushort_t xrow[3 * 34 * 64];    // idx ^= (cl&7)<<3 swizzle
    int blk = blockIdx.x;                      // 2048
    int b = blk >> 9, rem = blk & 511;
    int y = rem >> 2, xw = rem & 3;            // 32-px tile xw*32
    int xbase = (xw << 5) - 1;                 // x of cl=0
    int t = threadIdx.x;

#pragma unroll
    for (int i = 0; i < 4; ++i) {
        int t2 = i * 256 + t;
        if (t2 < 816) {                        // 3 rows x 34 cols x 8 chunks
            int ky = t2 / 272;
            int r2 = t2 - ky * 272;
            int cl = r2 >> 3, cj = r2 & 7;
            int yy = y + ky - 1;
            int xc = xbase + cl;
            bool ok = (yy >= 0) && (yy < HH) && (xc >= 0) && (xc < WW);
            uint4 v = make_uint4(0u, 0u, 0u, 0u);
            if (ok) v = *(const uint4*)&xtb[((size_t)b * HWp + yy * WW + xc) * CC + cj * 8];
            int idx = ((ky * 34 + cl) * 64 + cj * 8) ^ ((cl & 7) << 3);
            *(uint4*)&xrow[idx] = v;
        }
    }
    __syncthreads();

    int lane = t & 63, w = t >> 6;             // 4 waves: (mfc, nfc)
    int mfc = w & 1, nfc = w >> 1;
    int lm = lane & 15, lg = lane >> 4;
    int pxl = (nfc << 4) + lm;                 // 0..31 local
    f32x4 acc = {};
#pragma unroll
    for (int ks = 0; ks < 18; ++ks) {
        int kk = ks >> 1;
        int kyy = kk / 3, kxx = kk % 3;
        int c0 = (ks & 1) * 32 + lg * 8;
        short8 af = bc8(wpom[(ks * 2 + mfc) * 64 + lane]);
        int cl = pxl + kxx;
        int idx = ((kyy * 34 + cl) * 64 + c0) ^ ((cl & 7) << 3);
        short8 bf = *(const short8*)&xrow[idx];
        acc = __builtin_amdgcn_mfma_f32_16x16x32_bf16(af, bf, acc, 0, 0, 0);
    }
    int xg = (xw << 1) + nfc;                  // 16-px tile index 0..7
    size_t tb = ((size_t)((b * 128 + y) * 8 + xg)) * 432;
#pragma unroll
    for (int r = 0; r < 4; ++r) {
        int ch = (mfc << 4) + (lg << 2) + r;
        if (ch < 27) {
            float v = acc[r] + (ch < 18 ? b_off[ch] : b_mask[ch - 18]);
            if (ch >= 18) v = 1.f / (1.f + __expf(-v));
            om[tb + ch * 16 + lm] = v;
        }
    }
}

// ---------------- fused deform-gather + main GEMM (16 px, 256 thr) ----------
// LDS = 18.4 KB only -> 8 blocks/CU (32 waves). Params live in REGISTERS on
// lanes 0..35 (each wave owns 4 px x 9 taps) and are broadcast to 8-lane
// groups via __shfl. om reads come from the tiled layout (1.7 KB contiguous).
__global__ __launch_bounds__(256, 8) void k_fused(const ushort_t* __restrict__ xtb,
        const float* __restrict__ omt, const uint4* __restrict__ wpm,
        const float* __restrict__ bias, float* __restrict__ out) {
    __shared__ __align__(16) ushort_t sm[16 * 576];    // idx ^= ((px^k)&7)<<3
    int blk = blockIdx.x;                              // 4096
    int b = blk >> 10, rem = blk & 1023;
    int y = rem >> 3, xg = rem & 7, xs = xg << 4;
    int t = threadIdx.x, lane = t & 63, w = t >> 6;    // 4 waves
    const char* xbB = (const char*)xtb + ((size_t)b << 21);
    const float* omb = omt + ((size_t)((b * 128 + y) * 8 + xg)) * 432;

    // ---- phase 0: wave-local params in REGISTERS (lanes 0..35) ----
    float pw0 = 0.f, pw1 = 0.f, pw2 = 0.f, pw3 = 0.f;
    int paT = 0, paB = 0, ppk = 0;
    if (lane < 36) {
        int pxl = lane / 9, k = lane - pxl * 9;
        int px_t = (w << 2) + pxl;             // 0..15 in tile
        int ki = k / 3, kj = k - ki * 3;
        int x = xs + px_t;
        float dy = omb[32 * k + px_t];
        float dx = omb[32 * k + 16 + px_t];
        float m  = omb[288 + 16 * k + px_t];
        float sy = (float)(y - 1 + ki) + dy;
        float sx = (float)(x - 1 + kj) + dx;
        float fy = floorf(sy), fx = floorf(sx);
        float wy1 = sy - fy, wx1 = sx - fx;
        float wy0 = 1.f - wy1, wx0 = 1.f - wx1;
        int iy0 = (int)fy, ix0 = (int)fx;
        int iy1 = iy0 + 1, ix1 = ix0 + 1;
        bool vy0 = (iy0 >= 0) & (iy0 < HH);
        bool vy1 = (iy1 >= 0) & (iy1 < HH);
        float wyr0 = vy0 ? wy0 : (vy1 ? wy1 : 0.f);
        int   ry0  = vy0 ? iy0 : (vy1 ? iy1 : 0);
        float wyr1 = (vy0 & vy1) ? wy1 : 0.f;
        int   ry1  = min(max(iy1, 0), HH - 1);
        int bx = min(max(ix0, 0), WW - 2);
        float wxh0 = (bx == ix0) ? wx0 : ((bx == ix1) ? wx1 : 0.f);
        float wxh1 = (bx + 1 == ix1) ? wx1 : ((bx + 1 == ix0) ? wx0 : 0.f);
        pw0 = m * wyr0 * wxh0;
        pw1 = m * wyr0 * wxh1;
        pw2 = m * wyr1 * wxh0;
        pw3 = m * wyr1 * wxh1;
        paT = (int)((uint_t)(((ry0 << 7) + bx) << 7));
        paB = (int)((uint_t)(((ry1 << 7) + bx) << 7));
        ppk = (int)((uint_t)(px_t * 576 + k * 64) |
                    ((uint_t)(((px_t ^ k) & 7) << 3) << 16));
    }

    // ---- phase 1: 8-lane group = 1 sample, params via __shfl, pipelined ----
    {
        int g = lane >> 3, j = lane & 7;
        uint_t j16 = (uint_t)(j << 4);
        uint_t jw  = (uint_t)(j << 3);
        int slA = g;                            // round 0 sample
        float wA0 = __shfl(pw0, slA), wA1 = __shfl(pw1, slA);
        float wA2 = __shfl(pw2, slA), wA3 = __shfl(pw3, slA);
        uint_t aTA = (uint_t)__shfl(paT, slA) + j16;
        uint_t aBA = (uint_t)__shfl(paB, slA) + j16;
        uint_t pkA = (uint_t)__shfl(ppk, slA);
        uint4 tlA = *(const uint4*)(xbB + aTA);
        uint4 trA = *(const uint4*)(xbB + aTA + 128);
        uint4 blA = *(const uint4*)(xbB + aBA);
        uint4 brA = *(const uint4*)(xbB + aBA + 128);
#pragma unroll
        for (int r = 0; r < 5; ++r) {
            float wB0, wB1, wB2, wB3;
            uint_t pkB = 0;
            uint4 tlB, trB, blB, brB;
            if (r < 4) {
                int slB = g + (r + 1) * 8; slB = slB > 35 ? 35 : slB;
                wB0 = __shfl(pw0, slB); wB1 = __shfl(pw1, slB);
                wB2 = __shfl(pw2, slB); wB3 = __shfl(pw3, slB);
                uint_t aTB = (uint_t)__shfl(paT, slB) + j16;
                uint_t aBB = (uint_t)__shfl(paB, slB) + j16;
                pkB = (uint_t)__shfl(ppk, slB);
                tlB = *(const uint4*)(xbB + aTB);
                trB = *(const uint4*)(xbB + aTB + 128);
                blB = *(const uint4*)(xbB + aBB);
                brB = *(const uint4*)(xbB + aBB + 128);
            }
            f32x4 wv = { wA0, wA1, wA2, wA3 };
            short8 bf = bilerp8(wv, tlA, trA, blA, brA);
            if (r < 4 || g < 4) {
                uint_t widx = ((pkA & 0xFFFFu) + jw) ^ (pkA >> 16);
                *(short8*)&sm[widx] = bf;
            }
            wA0 = wB0; wA1 = wB1; wA2 = wB2; wA3 = wB3;
            pkA = pkB;
            tlA = tlB; trA = trB; blA = blB; brA = brB;
        }
    }
    __syncthreads();

    // ---- phase 2: out[64 x 16] = W(64x576) . sm(576x16); wave = mfrag ----
    int lm = lane & 15, lg = lane >> 4;
    f32x4 acc = {};
#pragma unroll
    for (int ks = 0; ks < 18; ++ks) {
        short8 af = bc8(wpm[((ks << 2) + w) * 64 + lane]);
        int bidx = (lm * 576 + (ks << 5) + (lg << 3)) ^ (((lm ^ (ks >> 1)) & 7) << 3);
        short8 bf = *(const short8*)&sm[bidx];
        acc = __builtin_amdgcn_mfma_f32_16x16x32_bf16(af, bf, acc, 0, 0, 0);
    }
#pragma unroll
    for (int r = 0; r < 4; ++r) {
        int o = (w << 4) + (lg << 2) + r;
        out[(((size_t)b * 64 + o) << 14) + (y << 7) + xs + lm] = acc[r] + bias[o];
    }
}

extern "C" void kernel_launch(void* const* d_in, const int* in_sizes, int n_in,
                              void* d_out, int out_size, void* d_ws, size_t ws_size,
                              hipStream_t stream) {
    const float* x      = (const float*)d_in[0];
    const float* w_off  = (const float*)d_in[1];
    const float* b_off  = (const float*)d_in[2];
    const float* w_mask = (const float*)d_in[3];
    const float* b_mask = (const float*)d_in[4];
    const float* w      = (const float*)d_in[5];
    const float* bias   = (const float*)d_in[6];
    float* out = (float*)d_out;

    char* ws = (char*)d_ws;
    ushort_t* xtb  = (ushort_t*)(ws);                    //  8,388,608 B
    float*    om   = (float*)(ws + 8388608);             //  7,077,888 B (tiled)
    ushort_t* wpom = (ushort_t*)(ws + 15466496);         //     36,864 B
    ushort_t* wpm  = (ushort_t*)(ws + 15503360);         //     73,728 B

    hipLaunchKernelGGL(k_prep, dim3(1240), dim3(256), 0, stream,
                       x, xtb, w_off, w_mask, w, wpom, wpm);
    hipLaunchKernelGGL(k_conv_om, dim3(2048), dim3(256), 0, stream,
                       xtb, (const uint4*)wpom, b_off, b_mask, om);
    hipLaunchKernelGGL(k_fused, dim3(4096), dim3(256), 0, stream,
                       xtb, om, (const uint4*)wpm, bias, out);
}